// Round 4
// baseline (548.444 us; speedup 1.0000x reference)
//
#include <hip/hip_runtime.h>
#include <hip/hip_bf16.h>

#define C_DIM 512
#define HW    4096
#define BATCH 4
#define PW    66
#define PPIX  (PW*PW)   // 4356

typedef __attribute__((ext_vector_type(8))) short bf16x8;
typedef __attribute__((ext_vector_type(4))) float f32x4;

static __device__ __forceinline__ short f2b(float f) {
    union { float f; unsigned u; } v; v.f = f;
    unsigned r = v.u + 0x7fffu + ((v.u >> 16) & 1u);
    return (short)(r >> 16);
}
static __device__ __forceinline__ float b2f(short s) {
    union { unsigned u; float f; } v; v.u = ((unsigned)(unsigned short)s) << 16;
    return v.f;
}

static __device__ __forceinline__ f32x4 zero4() {
    f32x4 v = {0.f, 0.f, 0.f, 0.f};
    return v;
}

static __device__ __forceinline__ void gload16(const void* g, void* l) {
    __builtin_amdgcn_global_load_lds(
        (__attribute__((address_space(1))) void*)g,
        (__attribute__((address_space(3))) void*)l, 16, 0, 0);
}

// ---------------- weight prep ----------------
__global__ void k_cvt_bf16(const float* __restrict__ in, short* __restrict__ out, int n) {
    int i = blockIdx.x * 256 + threadIdx.x;
    if (i < n) out[i] = f2b(in[i]);
}

__global__ void k_reorder_w3(const float* __restrict__ w, short* __restrict__ out) {
    int i = blockIdx.x * 256 + threadIdx.x;
    int c   = i & 511;
    int tap = (i >> 9) % 9;
    int o   = i / (9 * 512);
    out[i] = f2b(w[((size_t)o * 512 + c) * 9 + tap]);
}

// ---------------- layernorm ----------------
// 512 blocks x 256 thr; block covers 32 pixels, threads split C 8 ways.
__global__ void k_ln_stats(const float* __restrict__ x, float* __restrict__ mean,
                           float* __restrict__ rstd) {
    __shared__ float ss[8][32];
    __shared__ float sq2[8][32];
    int bid = blockIdx.x;
    int t = threadIdx.x;
    int px = t & 31, cg = t >> 5;
    int p = bid * 32 + px;             // global pixel id (b*4096 + pix)
    int b = p >> 12, pix = p & 4095;
    const float* xp = x + (size_t)b * C_DIM * HW + pix;
    float s = 0.f, sq = 0.f;
    #pragma unroll 4
    for (int c = cg * 64; c < cg * 64 + 64; ++c) {
        float v = xp[(size_t)c * HW];
        s += v; sq += v * v;
    }
    ss[cg][px] = s;
    sq2[cg][px] = sq;
    __syncthreads();
    if (t < 32) {
        float S = 0.f, Q = 0.f;
        #pragma unroll
        for (int j = 0; j < 8; ++j) { S += ss[j][t]; Q += sq2[j][t]; }
        float mu  = S * (1.0f / C_DIM);
        float var = Q * (1.0f / C_DIM) - mu * mu;
        int pg = bid * 32 + t;
        mean[pg] = mu;
        rstd[pg] = 1.0f / sqrtf(var + 1e-6f);
    }
}

__global__ void k_ln_apply(const float* __restrict__ x, const float* __restrict__ mean,
                           const float* __restrict__ rstd, const float* __restrict__ lnw,
                           const float* __restrict__ lnb, short* __restrict__ hp) {
    __shared__ short tile[64][65];
    int bid = blockIdx.x;
    int ct = bid & 7, y = (bid >> 3) & 63, b = bid >> 9;
    int c0 = ct * 64, p0 = y * 64;
    int t = threadIdx.x;
    int pi = t & 63, ci0 = t >> 6;
    int pg = (b << 12) + p0 + pi;
    float mu = mean[pg], rs = rstd[pg];
    const float* xb = x + (size_t)b * C_DIM * HW;
    #pragma unroll
    for (int cc = 0; cc < 64; cc += 4) {
        int c = c0 + cc + ci0;
        float v = xb[(size_t)c * HW + p0 + pi];
        tile[cc + ci0][pi] = f2b((v - mu) * rs * lnw[c] + lnb[c]);
    }
    __syncthreads();
    int cj = t & 63, pj = t >> 6;
    #pragma unroll
    for (int pp = 0; pp < 64; pp += 4) {
        int pidx = pp + pj;
        size_t dst = ((size_t)b * PPIX + (size_t)(y + 1) * PW + 1 + pidx) * C_DIM + c0 + cj;
        hp[dst] = tile[cj][pidx];
    }
}

// ---------------- conv-as-GEMM (q and proj) ----------------
template<int TAPS, int GMODE, int EPI>
__global__ __launch_bounds__(256, 2) void k_gemm(
        const short* __restrict__ A, const short* __restrict__ Bw,
        void* __restrict__ Out, const float* __restrict__ bias,
        const float* __restrict__ resid)
{
    constexpr int K = TAPS * 512;
    constexpr int NKC = K / 64;
    __shared__ short Alds[128 * 64];
    __shared__ short Blds[128 * 64];
    int bid = blockIdx.x;
    int mt = bid & 31, nt = (bid >> 5) & 3, b = bid >> 7;
    int m0 = mt * 128, n0 = nt * 128;
    int t = threadIdx.x;
    int lane = t & 63, w = t >> 6;
    int wm = w >> 1, wn = w & 1;
    int g = lane >> 4, li = lane & 15;
    int srow = t >> 3, schunk = t & 7;
    const short* Ab = A + (GMODE == 0 ? (size_t)b * PPIX * C_DIM : (size_t)b * HW * C_DIM);

    f32x4 acc[4][4];
    #pragma unroll
    for (int i = 0; i < 4; ++i)
        #pragma unroll
        for (int j = 0; j < 4; ++j) acc[i][j] = zero4();

    for (int kc = 0; kc < NKC; ++kc) {
        int tap = (TAPS == 9) ? (kc >> 3) : 4;
        int cb  = (kc & 7) * 64;
        __syncthreads();
        #pragma unroll
        for (int r = 0; r < 4; ++r) {
            int row = r * 32 + srow;
            size_t goff;
            if (GMODE == 0) {
                int m = m0 + row;
                int yy = m >> 6, xx = m & 63;
                int pp = (yy + tap / 3) * PW + xx + (tap % 3);
                goff = (size_t)pp * C_DIM + cb + schunk * 8;
            } else {
                goff = (size_t)(m0 + row) * K + kc * 64 + schunk * 8;
            }
            gload16(Ab + goff, Alds + row * 64 + schunk * 8);
        }
        #pragma unroll
        for (int r = 0; r < 4; ++r) {
            int row = r * 32 + srow;
            size_t goff = (size_t)(n0 + row) * K + kc * 64 + schunk * 8;
            gload16(Bw + goff, Blds + row * 64 + schunk * 8);
        }
        __syncthreads();
        #pragma unroll
        for (int ks = 0; ks < 2; ++ks) {
            int koff = ks * 32 + g * 8;
            bf16x8 af[4], bfr[4];
            #pragma unroll
            for (int i = 0; i < 4; ++i)
                af[i] = *(const bf16x8*)&Alds[(wm * 64 + i * 16 + li) * 64 + koff];
            #pragma unroll
            for (int j = 0; j < 4; ++j)
                bfr[j] = *(const bf16x8*)&Blds[(wn * 64 + j * 16 + li) * 64 + koff];
            #pragma unroll
            for (int i = 0; i < 4; ++i)
                #pragma unroll
                for (int j = 0; j < 4; ++j)
                    acc[i][j] = __builtin_amdgcn_mfma_f32_16x16x32_bf16(af[i], bfr[j], acc[i][j], 0, 0, 0);
        }
    }
    #pragma unroll
    for (int fm = 0; fm < 4; ++fm) {
        #pragma unroll
        for (int fn = 0; fn < 4; ++fn) {
            int mrow = m0 + wm * 64 + fm * 16 + g * 4;
            int ncol = n0 + wn * 64 + fn * 16 + li;
            if constexpr (EPI == 0) {
                #pragma unroll
                for (int i = 0; i < 4; ++i) {
                    size_t dst = ((size_t)b * HW + mrow + i) * C_DIM + ncol;
                    ((short*)Out)[dst] = f2b(acc[fm][fn][i]);
                }
            } else if constexpr (EPI == 1) {
                size_t dst = ((size_t)b * C_DIM + ncol) * HW + mrow;
                short4 sv = make_short4(f2b(acc[fm][fn][0]), f2b(acc[fm][fn][1]),
                                        f2b(acc[fm][fn][2]), f2b(acc[fm][fn][3]));
                *(short4*)((short*)Out + dst) = sv;
            } else {
                size_t dst = ((size_t)b * C_DIM + ncol) * HW + mrow;
                float bb = bias[ncol];
                float4 xr = *(const float4*)(resid + dst);
                float4 o;
                o.x = acc[fm][fn][0] + bb + xr.x;
                o.y = acc[fm][fn][1] + bb + xr.y;
                o.z = acc[fm][fn][2] + bb + xr.z;
                o.w = acc[fm][fn][3] + bb + xr.w;
                *(float4*)((float*)Out + dst) = o;
            }
        }
    }
}

// ---------------- fused K+V 3x3 conv ----------------
__global__ __launch_bounds__(256, 2) void k_gemm_kv(
        const short* __restrict__ A, const short* __restrict__ Bk,
        const short* __restrict__ Bv, short* __restrict__ OutK,
        short* __restrict__ OutV)
{
    constexpr int K = 4608;
    __shared__ short Alds[128 * 64];
    __shared__ short Bklds[128 * 64];
    __shared__ short Bvlds[128 * 64];
    int bid = blockIdx.x;
    int mt = bid & 31, nt = (bid >> 5) & 3, b = bid >> 7;
    int m0 = mt * 128, n0 = nt * 128;
    int t = threadIdx.x;
    int lane = t & 63, w = t >> 6;
    int wm = w >> 1, wn = w & 1;
    int g = lane >> 4, li = lane & 15;
    int srow = t >> 3, schunk = t & 7;
    const short* Ab = A + (size_t)b * PPIX * C_DIM;

    f32x4 accK[4][4], accV[4][4];
    #pragma unroll
    for (int i = 0; i < 4; ++i)
        #pragma unroll
        for (int j = 0; j < 4; ++j) { accK[i][j] = zero4(); accV[i][j] = zero4(); }

    for (int kc = 0; kc < 72; ++kc) {
        int tap = kc >> 3;
        int cb  = (kc & 7) * 64;
        __syncthreads();
        #pragma unroll
        for (int r = 0; r < 4; ++r) {
            int row = r * 32 + srow;
            int m = m0 + row;
            int yy = m >> 6, xx = m & 63;
            int pp = (yy + tap / 3) * PW + xx + (tap % 3);
            gload16(Ab + (size_t)pp * C_DIM + cb + schunk * 8, Alds + row * 64 + schunk * 8);
        }
        #pragma unroll
        for (int r = 0; r < 4; ++r) {
            int row = r * 32 + srow;
            size_t goff = (size_t)(n0 + row) * K + kc * 64 + schunk * 8;
            gload16(Bk + goff, Bklds + row * 64 + schunk * 8);
            gload16(Bv + goff, Bvlds + row * 64 + schunk * 8);
        }
        __syncthreads();
        #pragma unroll
        for (int ks = 0; ks < 2; ++ks) {
            int koff = ks * 32 + g * 8;
            bf16x8 af[4], bk[4], bv[4];
            #pragma unroll
            for (int i = 0; i < 4; ++i)
                af[i] = *(const bf16x8*)&Alds[(wm * 64 + i * 16 + li) * 64 + koff];
            #pragma unroll
            for (int j = 0; j < 4; ++j)
                bk[j] = *(const bf16x8*)&Bklds[(wn * 64 + j * 16 + li) * 64 + koff];
            #pragma unroll
            for (int i = 0; i < 4; ++i)
                #pragma unroll
                for (int j = 0; j < 4; ++j)
                    accK[i][j] = __builtin_amdgcn_mfma_f32_16x16x32_bf16(af[i], bk[j], accK[i][j], 0, 0, 0);
            #pragma unroll
            for (int j = 0; j < 4; ++j)
                bv[j] = *(const bf16x8*)&Bvlds[(wn * 64 + j * 16 + li) * 64 + koff];
            #pragma unroll
            for (int i = 0; i < 4; ++i)
                #pragma unroll
                for (int j = 0; j < 4; ++j)
                    accV[i][j] = __builtin_amdgcn_mfma_f32_16x16x32_bf16(af[i], bv[j], accV[i][j], 0, 0, 0);
        }
    }
    #pragma unroll
    for (int fm = 0; fm < 4; ++fm) {
        #pragma unroll
        for (int fn = 0; fn < 4; ++fn) {
            int mrow = m0 + wm * 64 + fm * 16 + g * 4;
            int ncol = n0 + wn * 64 + fn * 16 + li;
            #pragma unroll
            for (int i = 0; i < 4; ++i) {
                size_t dst = ((size_t)b * HW + mrow + i) * C_DIM + ncol;
                OutK[dst] = f2b(accK[fm][fn][i]);
            }
            size_t dstv = ((size_t)b * C_DIM + ncol) * HW + mrow;
            short4 sv = make_short4(f2b(accV[fm][fn][0]), f2b(accV[fm][fn][1]),
                                    f2b(accV[fm][fn][2]), f2b(accV[fm][fn][3]));
            *(short4*)(OutV + dstv) = sv;
        }
    }
}

// ---------------- flash attention, round 4: q=32/wave, 4 waves, 1 wave/SIMD ----
// Each K/V fragment read from LDS now feeds TWO query-halves -> LDS read
// traffic halved vs round 3. Full 512-reg file per wave (1 wave/SIMD).
#define KT 32
#define NTILES 64
__global__ __launch_bounds__(256, 1) void k_attn(
        const short* __restrict__ qT, const short* __restrict__ kT,
        const short* __restrict__ vg, short* __restrict__ O0,
        short* __restrict__ O1, float* __restrict__ L0, float* __restrict__ L1)
{
    __shared__ short Klds[2][KT * 512];   // chunk P = ccol*32 + key
    __shared__ short Vlds[2][512 * KT];   // chunk P = ccol*512 + ch
    __shared__ short Plds[4][32 * 40];    // per-wave, 32 q rows x 80B

    int bid = blockIdx.x;
    int qt = bid & 31, ks = (bid >> 5) & 1, b = bid >> 6;
    int m0 = qt * 128;
    int t = threadIdx.x, lane = t & 63, w = t >> 6;   // w: 0..3
    int g = lane >> 4, li = lane & 15;

    const short* kb = kT + (size_t)b * HW * C_DIM + (size_t)ks * 2048 * C_DIM;
    const short* vb = vg + (size_t)b * C_DIM * HW + ks * 2048;

    // Q fragments: 32 q rows per wave (two halves), 128 VGPR
    bf16x8 qf[2][16];
    #pragma unroll
    for (int qh = 0; qh < 2; ++qh) {
        const short* qrow = qT + ((size_t)b * HW + m0 + w * 32 + qh * 16 + li) * C_DIM;
        #pragma unroll
        for (int kc = 0; kc < 16; ++kc)
            qf[qh][kc] = *(const bf16x8*)&qrow[kc * 32 + g * 8];
    }
    f32x4 oacc[2][32];
    #pragma unroll
    for (int qh = 0; qh < 2; ++qh)
        #pragma unroll
        for (int i = 0; i < 32; ++i) oacc[qh][i] = zero4();
    float lsum0 = 0.f, lsum1 = 0.f;

    // staging sources (chunk-transpose permutation on the global side)
    const short* ksrc = kb + (size_t)(t & 31) * 512 + (t >> 5) * 8;
    const short* vsrc = vb + (size_t)t * 4096;

    const int klane = g * 256 + li * 8;
    const int vlane = g * 4096 + li * 8;
    const float SC = 0.044194173824159216f * 1.4426950408889634f; // 512^-0.5 * log2(e)

    auto STAGE = [&](int buf, int nt) {
        int n0 = nt * KT;
        const short* kS = ksrc + (size_t)n0 * 512;
        short* kD = (short*)Klds[buf] + t * 8;
        #pragma unroll
        for (int r = 0; r < 8; ++r)                    // chunk P = t + r*256
            gload16(kS + r * 64, kD + r * 2048);
        short* vD = (short*)Vlds[buf] + t * 8;
        #pragma unroll
        for (int r = 0; r < 8; ++r)                    // ch = t + (r&1)*256, ccol = r>>1
            gload16(vsrc + (size_t)(r & 1) * 1048576 + (r >> 1) * 8 + n0,
                    vD + r * 2048);
    };

    auto COMPUTE = [&](int buf) {
        const short* kbase = (const short*)Klds[buf] + klane;
        const short* vbase = (const short*)Vlds[buf] + vlane;
        f32x4 s[2][2];
        s[0][0] = zero4(); s[0][1] = zero4(); s[1][0] = zero4(); s[1][1] = zero4();
        #pragma unroll
        for (int kc = 0; kc < 16; ++kc) {
            bf16x8 kf0 = *(const bf16x8*)&kbase[kc * 1024];
            bf16x8 kf1 = *(const bf16x8*)&kbase[kc * 1024 + 128];
            s[0][0] = __builtin_amdgcn_mfma_f32_16x16x32_bf16(kf0, qf[0][kc], s[0][0], 0, 0, 0);
            s[1][0] = __builtin_amdgcn_mfma_f32_16x16x32_bf16(kf0, qf[1][kc], s[1][0], 0, 0, 0);
            s[0][1] = __builtin_amdgcn_mfma_f32_16x16x32_bf16(kf1, qf[0][kc], s[0][1], 0, 0, 0);
            s[1][1] = __builtin_amdgcn_mfma_f32_16x16x32_bf16(kf1, qf[1][kc], s[1][1], 0, 0, 0);
        }
        // softmax (no-max): lane holds keys fn*16+g*4+i for query li (per half)
        #pragma unroll
        for (int qh = 0; qh < 2; ++qh) {
            #pragma unroll
            for (int fn = 0; fn < 2; ++fn) {
                float e0 = exp2f(s[qh][fn][0] * SC);
                float e1 = exp2f(s[qh][fn][1] * SC);
                float e2 = exp2f(s[qh][fn][2] * SC);
                float e3 = exp2f(s[qh][fn][3] * SC);
                if (qh == 0) lsum0 += (e0 + e1) + (e2 + e3);
                else         lsum1 += (e0 + e1) + (e2 + e3);
                union { __hip_bfloat162 h; unsigned u; } p01, p23;
                p01.h = __float22bfloat162_rn(make_float2(e0, e1));
                p23.h = __float22bfloat162_rn(make_float2(e2, e3));
                uint2 pk = make_uint2(p01.u, p23.u);
                *(uint2*)&Plds[w][(qh * 16 + li) * 40 + fn * 16 + g * 4] = pk;
            }
        }
        asm volatile("s_waitcnt lgkmcnt(0)" ::: "memory");
        __builtin_amdgcn_sched_barrier(0);
        bf16x8 pf0 = *(const bf16x8*)&Plds[w][li * 40 + g * 8];
        bf16x8 pf1 = *(const bf16x8*)&Plds[w][(16 + li) * 40 + g * 8];
        #pragma unroll
        for (int cf = 0; cf < 32; ++cf) {
            bf16x8 vf = *(const bf16x8*)&vbase[cf * 128];
            oacc[0][cf] = __builtin_amdgcn_mfma_f32_16x16x32_bf16(pf0, vf, oacc[0][cf], 0, 0, 0);
            oacc[1][cf] = __builtin_amdgcn_mfma_f32_16x16x32_bf16(pf1, vf, oacc[1][cf], 0, 0, 0);
        }
    };

    STAGE(0, 0);
    asm volatile("s_waitcnt vmcnt(0)" ::: "memory");
    __builtin_amdgcn_s_barrier();
    __builtin_amdgcn_sched_barrier(0);

    int buf = 0;
    for (int nt = 0; nt < NTILES - 1; ++nt) {
        STAGE(buf ^ 1, nt + 1);
        COMPUTE(buf);
        asm volatile("s_waitcnt vmcnt(0)" ::: "memory");
        __builtin_amdgcn_s_barrier();
        __builtin_amdgcn_sched_barrier(0);
        buf ^= 1;
    }
    COMPUTE(buf);

    // reduce per-query sums across g-groups
    lsum0 += __shfl_xor(lsum0, 16);
    lsum0 += __shfl_xor(lsum0, 32);
    lsum1 += __shfl_xor(lsum1, 16);
    lsum1 += __shfl_xor(lsum1, 32);
    float* Lb = (ks ? L1 : L0) + (size_t)b * HW + m0 + w * 32;
    if (lane < 16) {
        Lb[lane] = lsum0;
        Lb[16 + lane] = lsum1;
    }
    short* Ob = (ks ? O1 : O0) + ((size_t)b * HW + m0 + w * 32) * C_DIM;
    #pragma unroll
    for (int qh = 0; qh < 2; ++qh)
        #pragma unroll
        for (int cf = 0; cf < 32; ++cf)
            #pragma unroll
            for (int i = 0; i < 4; ++i) {
                int q = qh * 16 + g * 4 + i;
                Ob[(size_t)q * C_DIM + cf * 16 + li] = f2b(oacc[qh][cf][i]);
            }
}

__global__ void k_att_comb(const short* __restrict__ O0, const short* __restrict__ O1,
                           const float* __restrict__ L0, const float* __restrict__ L1,
                           short* __restrict__ oatt) {
    int i = blockIdx.x * 256 + threadIdx.x;
    int row = i >> 6;
    int c0 = (i & 63) * 8;
    float r = 1.0f / (L0[row] + L1[row]);
    size_t base = (size_t)row * C_DIM + c0;
    bf16x8 a = *(const bf16x8*)&O0[base];
    bf16x8 c = *(const bf16x8*)&O1[base];
    bf16x8 o;
    #pragma unroll
    for (int j = 0; j < 8; ++j)
        o[j] = f2b((b2f(a[j]) + b2f(c[j])) * r);
    *(bf16x8*)&oatt[base] = o;
}

// ---------------- launch ----------------
extern "C" void kernel_launch(void* const* d_in, const int* in_sizes, int n_in,
                              void* d_out, int out_size, void* d_ws, size_t ws_size,
                              hipStream_t stream) {
    const float* x    = (const float*)d_in[0];
    const float* ln_w = (const float*)d_in[1];
    const float* ln_b = (const float*)d_in[2];
    const float* wq   = (const float*)d_in[3];
    const float* wk   = (const float*)d_in[4];
    const float* wv   = (const float*)d_in[5];
    const float* wp   = (const float*)d_in[6];
    const float* bp   = (const float*)d_in[7];
    float* out = (float*)d_out;

    char* ws = (char*)d_ws;
    size_t off = 0;
    auto alloc = [&](size_t bytes) {
        char* p = ws + off;
        off += (bytes + 255) & ~(size_t)255;
        return p;
    };
    short* hp   = (short*)alloc((size_t)BATCH * PPIX * C_DIM * 2);   // also O-partial 0
    short* wqb  = (short*)alloc((size_t)512 * 512 * 2);
    short* wkr  = (short*)alloc((size_t)512 * 4608 * 2);
    short* wvr  = (short*)alloc((size_t)512 * 4608 * 2);
    short* wpb  = (short*)alloc((size_t)512 * 512 * 2);
    short* qT   = (short*)alloc((size_t)BATCH * HW * C_DIM * 2);
    short* kT   = (short*)alloc((size_t)BATCH * HW * C_DIM * 2);
    short* vg   = (short*)alloc((size_t)BATCH * HW * C_DIM * 2);
    short* oatt = (short*)alloc((size_t)BATCH * HW * C_DIM * 2);     // also O-partial 1
    float* mean = (float*)alloc((size_t)BATCH * HW * 4);             // also Lsum 0
    float* rstd = (float*)alloc((size_t)BATCH * HW * 4);             // also Lsum 1

    hipMemsetAsync(hp, 0, (size_t)BATCH * PPIX * C_DIM * 2, stream);
    k_cvt_bf16<<<1024, 256, 0, stream>>>(wq, wqb, 512 * 512);
    k_cvt_bf16<<<1024, 256, 0, stream>>>(wp, wpb, 512 * 512);
    k_reorder_w3<<<9216, 256, 0, stream>>>(wk, wkr);
    k_reorder_w3<<<9216, 256, 0, stream>>>(wv, wvr);
    k_ln_stats<<<512, 256, 0, stream>>>(x, mean, rstd);
    k_ln_apply<<<2048, 256, 0, stream>>>(x, mean, rstd, ln_w, ln_b, hp);

    k_gemm<1, 0, 0><<<512, 256, 0, stream>>>(hp, wqb, qT, nullptr, nullptr);
    k_gemm_kv<<<512, 256, 0, stream>>>(hp, wkr, wvr, kT, vg);

    short* Op0 = hp;
    short* Op1 = oatt;
    float* Ls0 = mean;
    float* Ls1 = rstd;
    k_attn<<<256, 256, 0, stream>>>(qT, kT, vg, Op0, Op1, Ls0, Ls1);
    k_att_comb<<<4096, 256, 0, stream>>>(Op0, Op1, Ls0, Ls1, oatt);

    k_gemm<1, 1, 2><<<512, 256, 0, stream>>>(oatt, wpb, out, bp, x);
}

// Round 5
// 410.110 us; speedup vs baseline: 1.3373x; 1.3373x over previous
//
#include <hip/hip_runtime.h>
#include <hip/hip_bf16.h>

#define C_DIM 512
#define HW    4096
#define BATCH 4
#define PW    66
#define PPIX  (PW*PW)   // 4356

typedef __attribute__((ext_vector_type(8))) short bf16x8;
typedef __attribute__((ext_vector_type(4))) float f32x4;
typedef __attribute__((ext_vector_type(16))) float f32x16;

static __device__ __forceinline__ short f2b(float f) {
    union { float f; unsigned u; } v; v.f = f;
    unsigned r = v.u + 0x7fffu + ((v.u >> 16) & 1u);
    return (short)(r >> 16);
}
static __device__ __forceinline__ float b2f(short s) {
    union { unsigned u; float f; } v; v.u = ((unsigned)(unsigned short)s) << 16;
    return v.f;
}

static __device__ __forceinline__ f32x4 zero4() {
    f32x4 v = {0.f, 0.f, 0.f, 0.f};
    return v;
}
static __device__ __forceinline__ f32x16 zero16() {
    f32x16 v = {0.f,0.f,0.f,0.f, 0.f,0.f,0.f,0.f, 0.f,0.f,0.f,0.f, 0.f,0.f,0.f,0.f};
    return v;
}

static __device__ __forceinline__ void gload16(const void* g, void* l) {
    __builtin_amdgcn_global_load_lds(
        (__attribute__((address_space(1))) void*)g,
        (__attribute__((address_space(3))) void*)l, 16, 0, 0);
}

// ---------------- weight prep ----------------
__global__ void k_cvt_bf16(const float* __restrict__ in, short* __restrict__ out, int n) {
    int i = blockIdx.x * 256 + threadIdx.x;
    if (i < n) out[i] = f2b(in[i]);
}

__global__ void k_reorder_w3(const float* __restrict__ w, short* __restrict__ out) {
    int i = blockIdx.x * 256 + threadIdx.x;
    int c   = i & 511;
    int tap = (i >> 9) % 9;
    int o   = i / (9 * 512);
    out[i] = f2b(w[((size_t)o * 512 + c) * 9 + tap]);
}

// ---------------- layernorm ----------------
__global__ void k_ln_stats(const float* __restrict__ x, float* __restrict__ mean,
                           float* __restrict__ rstd) {
    __shared__ float ss[8][32];
    __shared__ float sq2[8][32];
    int bid = blockIdx.x;
    int t = threadIdx.x;
    int px = t & 31, cg = t >> 5;
    int p = bid * 32 + px;
    int b = p >> 12, pix = p & 4095;
    const float* xp = x + (size_t)b * C_DIM * HW + pix;
    float s = 0.f, sq = 0.f;
    #pragma unroll 4
    for (int c = cg * 64; c < cg * 64 + 64; ++c) {
        float v = xp[(size_t)c * HW];
        s += v; sq += v * v;
    }
    ss[cg][px] = s;
    sq2[cg][px] = sq;
    __syncthreads();
    if (t < 32) {
        float S = 0.f, Q = 0.f;
        #pragma unroll
        for (int j = 0; j < 8; ++j) { S += ss[j][t]; Q += sq2[j][t]; }
        float mu  = S * (1.0f / C_DIM);
        float var = Q * (1.0f / C_DIM) - mu * mu;
        int pg = bid * 32 + t;
        mean[pg] = mu;
        rstd[pg] = 1.0f / sqrtf(var + 1e-6f);
    }
}

__global__ void k_ln_apply(const float* __restrict__ x, const float* __restrict__ mean,
                           const float* __restrict__ rstd, const float* __restrict__ lnw,
                           const float* __restrict__ lnb, short* __restrict__ hp) {
    __shared__ short tile[64][65];
    int bid = blockIdx.x;
    int ct = bid & 7, y = (bid >> 3) & 63, b = bid >> 9;
    int c0 = ct * 64, p0 = y * 64;
    int t = threadIdx.x;
    int pi = t & 63, ci0 = t >> 6;
    int pg = (b << 12) + p0 + pi;
    float mu = mean[pg], rs = rstd[pg];
    const float* xb = x + (size_t)b * C_DIM * HW;
    #pragma unroll
    for (int cc = 0; cc < 64; cc += 4) {
        int c = c0 + cc + ci0;
        float v = xb[(size_t)c * HW + p0 + pi];
        tile[cc + ci0][pi] = f2b((v - mu) * rs * lnw[c] + lnb[c]);
    }
    __syncthreads();
    int cj = t & 63, pj = t >> 6;
    #pragma unroll
    for (int pp = 0; pp < 64; pp += 4) {
        int pidx = pp + pj;
        size_t dst = ((size_t)b * PPIX + (size_t)(y + 1) * PW + 1 + pidx) * C_DIM + c0 + cj;
        hp[dst] = tile[cj][pidx];
    }
}

// ---------------- conv-as-GEMM (q and proj) ----------------
template<int TAPS, int GMODE, int EPI>
__global__ __launch_bounds__(256, 2) void k_gemm(
        const short* __restrict__ A, const short* __restrict__ Bw,
        void* __restrict__ Out, const float* __restrict__ bias,
        const float* __restrict__ resid)
{
    constexpr int K = TAPS * 512;
    constexpr int NKC = K / 64;
    __shared__ short Alds[128 * 64];
    __shared__ short Blds[128 * 64];
    int bid = blockIdx.x;
    int mt = bid & 31, nt = (bid >> 5) & 3, b = bid >> 7;
    int m0 = mt * 128, n0 = nt * 128;
    int t = threadIdx.x;
    int lane = t & 63, w = t >> 6;
    int wm = w >> 1, wn = w & 1;
    int g = lane >> 4, li = lane & 15;
    int srow = t >> 3, schunk = t & 7;
    const short* Ab = A + (GMODE == 0 ? (size_t)b * PPIX * C_DIM : (size_t)b * HW * C_DIM);

    f32x4 acc[4][4];
    #pragma unroll
    for (int i = 0; i < 4; ++i)
        #pragma unroll
        for (int j = 0; j < 4; ++j) acc[i][j] = zero4();

    for (int kc = 0; kc < NKC; ++kc) {
        int tap = (TAPS == 9) ? (kc >> 3) : 4;
        int cb  = (kc & 7) * 64;
        __syncthreads();
        #pragma unroll
        for (int r = 0; r < 4; ++r) {
            int row = r * 32 + srow;
            size_t goff;
            if (GMODE == 0) {
                int m = m0 + row;
                int yy = m >> 6, xx = m & 63;
                int pp = (yy + tap / 3) * PW + xx + (tap % 3);
                goff = (size_t)pp * C_DIM + cb + schunk * 8;
            } else {
                goff = (size_t)(m0 + row) * K + kc * 64 + schunk * 8;
            }
            gload16(Ab + goff, Alds + row * 64 + schunk * 8);
        }
        #pragma unroll
        for (int r = 0; r < 4; ++r) {
            int row = r * 32 + srow;
            size_t goff = (size_t)(n0 + row) * K + kc * 64 + schunk * 8;
            gload16(Bw + goff, Blds + row * 64 + schunk * 8);
        }
        __syncthreads();
        #pragma unroll
        for (int ks = 0; ks < 2; ++ks) {
            int koff = ks * 32 + g * 8;
            bf16x8 af[4], bfr[4];
            #pragma unroll
            for (int i = 0; i < 4; ++i)
                af[i] = *(const bf16x8*)&Alds[(wm * 64 + i * 16 + li) * 64 + koff];
            #pragma unroll
            for (int j = 0; j < 4; ++j)
                bfr[j] = *(const bf16x8*)&Blds[(wn * 64 + j * 16 + li) * 64 + koff];
            #pragma unroll
            for (int i = 0; i < 4; ++i)
                #pragma unroll
                for (int j = 0; j < 4; ++j)
                    acc[i][j] = __builtin_amdgcn_mfma_f32_16x16x32_bf16(af[i], bfr[j], acc[i][j], 0, 0, 0);
        }
    }
    #pragma unroll
    for (int fm = 0; fm < 4; ++fm) {
        #pragma unroll
        for (int fn = 0; fn < 4; ++fn) {
            int mrow = m0 + wm * 64 + fm * 16 + g * 4;
            int ncol = n0 + wn * 64 + fn * 16 + li;
            if constexpr (EPI == 0) {
                #pragma unroll
                for (int i = 0; i < 4; ++i) {
                    size_t dst = ((size_t)b * HW + mrow + i) * C_DIM + ncol;
                    ((short*)Out)[dst] = f2b(acc[fm][fn][i]);
                }
            } else if constexpr (EPI == 1) {
                size_t dst = ((size_t)b * C_DIM + ncol) * HW + mrow;
                short4 sv = make_short4(f2b(acc[fm][fn][0]), f2b(acc[fm][fn][1]),
                                        f2b(acc[fm][fn][2]), f2b(acc[fm][fn][3]));
                *(short4*)((short*)Out + dst) = sv;
            } else {
                size_t dst = ((size_t)b * C_DIM + ncol) * HW + mrow;
                float bb = bias[ncol];
                float4 xr = *(const float4*)(resid + dst);
                float4 o;
                o.x = acc[fm][fn][0] + bb + xr.x;
                o.y = acc[fm][fn][1] + bb + xr.y;
                o.z = acc[fm][fn][2] + bb + xr.z;
                o.w = acc[fm][fn][3] + bb + xr.w;
                *(float4*)((float*)Out + dst) = o;
            }
        }
    }
}

// ---------------- fused K+V 3x3 conv ----------------
__global__ __launch_bounds__(256, 2) void k_gemm_kv(
        const short* __restrict__ A, const short* __restrict__ Bk,
        const short* __restrict__ Bv, short* __restrict__ OutK,
        short* __restrict__ OutV)
{
    constexpr int K = 4608;
    __shared__ short Alds[128 * 64];
    __shared__ short Bklds[128 * 64];
    __shared__ short Bvlds[128 * 64];
    int bid = blockIdx.x;
    int mt = bid & 31, nt = (bid >> 5) & 3, b = bid >> 7;
    int m0 = mt * 128, n0 = nt * 128;
    int t = threadIdx.x;
    int lane = t & 63, w = t >> 6;
    int wm = w >> 1, wn = w & 1;
    int g = lane >> 4, li = lane & 15;
    int srow = t >> 3, schunk = t & 7;
    const short* Ab = A + (size_t)b * PPIX * C_DIM;

    f32x4 accK[4][4], accV[4][4];
    #pragma unroll
    for (int i = 0; i < 4; ++i)
        #pragma unroll
        for (int j = 0; j < 4; ++j) { accK[i][j] = zero4(); accV[i][j] = zero4(); }

    for (int kc = 0; kc < 72; ++kc) {
        int tap = kc >> 3;
        int cb  = (kc & 7) * 64;
        __syncthreads();
        #pragma unroll
        for (int r = 0; r < 4; ++r) {
            int row = r * 32 + srow;
            int m = m0 + row;
            int yy = m >> 6, xx = m & 63;
            int pp = (yy + tap / 3) * PW + xx + (tap % 3);
            gload16(Ab + (size_t)pp * C_DIM + cb + schunk * 8, Alds + row * 64 + schunk * 8);
        }
        #pragma unroll
        for (int r = 0; r < 4; ++r) {
            int row = r * 32 + srow;
            size_t goff = (size_t)(n0 + row) * K + kc * 64 + schunk * 8;
            gload16(Bk + goff, Bklds + row * 64 + schunk * 8);
            gload16(Bv + goff, Bvlds + row * 64 + schunk * 8);
        }
        __syncthreads();
        #pragma unroll
        for (int ks = 0; ks < 2; ++ks) {
            int koff = ks * 32 + g * 8;
            bf16x8 af[4], bk[4], bv[4];
            #pragma unroll
            for (int i = 0; i < 4; ++i)
                af[i] = *(const bf16x8*)&Alds[(wm * 64 + i * 16 + li) * 64 + koff];
            #pragma unroll
            for (int j = 0; j < 4; ++j)
                bk[j] = *(const bf16x8*)&Bklds[(wn * 64 + j * 16 + li) * 64 + koff];
            #pragma unroll
            for (int i = 0; i < 4; ++i)
                #pragma unroll
                for (int j = 0; j < 4; ++j)
                    accK[i][j] = __builtin_amdgcn_mfma_f32_16x16x32_bf16(af[i], bk[j], accK[i][j], 0, 0, 0);
            #pragma unroll
            for (int j = 0; j < 4; ++j)
                bv[j] = *(const bf16x8*)&Bvlds[(wn * 64 + j * 16 + li) * 64 + koff];
            #pragma unroll
            for (int i = 0; i < 4; ++i)
                #pragma unroll
                for (int j = 0; j < 4; ++j)
                    accV[i][j] = __builtin_amdgcn_mfma_f32_16x16x32_bf16(af[i], bv[j], accV[i][j], 0, 0, 0);
        }
    }
    #pragma unroll
    for (int fm = 0; fm < 4; ++fm) {
        #pragma unroll
        for (int fn = 0; fn < 4; ++fn) {
            int mrow = m0 + wm * 64 + fm * 16 + g * 4;
            int ncol = n0 + wn * 64 + fn * 16 + li;
            #pragma unroll
            for (int i = 0; i < 4; ++i) {
                size_t dst = ((size_t)b * HW + mrow + i) * C_DIM + ncol;
                OutK[dst] = f2b(accK[fm][fn][i]);
            }
            size_t dstv = ((size_t)b * C_DIM + ncol) * HW + mrow;
            short4 sv = make_short4(f2b(accV[fm][fn][0]), f2b(accV[fm][fn][1]),
                                    f2b(accV[fm][fn][2]), f2b(accV[fm][fn][3]));
            *(short4*)(OutV + dstv) = sv;
        }
    }
}

// ---------------- flash attention, round 5 ----------------
// 8 waves (2/SIMD), QB=128. QK: round-3 16x16 path, q=16/wave, P -> block LDS
// (128q x 32k, 80B rows). PV: 32x32x16 mfma(V, P): each wave computes ALL 128
// queries x its 64 channels (oacc 8 x f32x16 = 128 VGPR). V in LDS as [ch][key]
// 80B rows. O written via per-wave LDS transpose -> coalesced [b][m][c].
#define KT 32
#define NTILES 64
__global__ __launch_bounds__(512, 2) void k_attn(
        const short* __restrict__ qT, const short* __restrict__ kT,
        const short* __restrict__ vg, short* __restrict__ O0,
        short* __restrict__ O1, float* __restrict__ L0, float* __restrict__ L1)
{
    __shared__ __align__(16) short pool[78848];
    short* Kp = pool;               // 2 x 16384 shorts (K: chunk P=ccol*32+key)
    short* Vp = pool + 32768;       // 2 x 20480 shorts (V: [ch][40] rows, 4 data chunks + pad)
    short* Pp = pool + 73728;       // 5120 shorts     (P: [128][40] rows)

    int bid0 = blockIdx.x;
    int bid = (bid0 & 7) * 32 + (bid0 >> 3);   // XCD swizzle: one (ks,b) pair per XCD
    int qt = bid & 31, ks = (bid >> 5) & 1, b = bid >> 6;
    int m0 = qt * 128;
    int t = threadIdx.x, lane = t & 63, w = t >> 6;
    int g = lane >> 4, li = lane & 15;
    int l31 = lane & 31, l5 = lane >> 5;

    const short* kb = kT + (size_t)b * HW * C_DIM + (size_t)ks * 2048 * C_DIM;
    const short* vb = vg + (size_t)b * C_DIM * HW + ks * 2048;

    // Q fragments (16 q rows per wave, 64 VGPR)
    bf16x8 qf[16];
    {
        const short* qrow = qT + ((size_t)b * HW + m0 + w * 16 + li) * C_DIM;
        #pragma unroll
        for (int kc = 0; kc < 16; ++kc)
            qf[kc] = *(const bf16x8*)&qrow[kc * 32 + g * 8];
    }
    f32x16 oacc[8];
    #pragma unroll
    for (int a = 0; a < 8; ++a) oacc[a] = zero16();
    float lsum = 0.f;

    // K staging source (chunk-transposed, proven in r3)
    const short* ksrc = kb + (size_t)(t & 31) * 512 + (t >> 5) * 8;
    // V staging: dest chunk D = r*512+t -> (ch=D/5, c=D%5); c==4 is pad (dummy src)
    int voff[5];
    #pragma unroll
    for (int r = 0; r < 5; ++r) {
        int D = r * 512 + t;
        int ch = D / 5;
        int c  = D - ch * 5;
        voff[r] = (c < 4) ? ch * 4096 + c * 8 : 0;
    }

    const float SC = 0.044194173824159216f * 1.4426950408889634f; // 512^-0.5 * log2(e)

    auto STAGE = [&](int buf, int nt) {
        int n0 = nt * KT;
        const short* kS = ksrc + (size_t)n0 * 512;
        short* kD = Kp + buf * 16384 + t * 8;
        #pragma unroll
        for (int r = 0; r < 4; ++r)
            gload16(kS + r * 128, kD + r * 4096);
        short* vD = Vp + buf * 20480 + t * 8;
        #pragma unroll
        for (int r = 0; r < 5; ++r)
            gload16(vb + voff[r] + n0, vD + r * 4096);
    };

    STAGE(0, 0);
    __syncthreads();

    int buf = 0;
    for (int nt = 0; nt < NTILES; ++nt) {
        if (nt < NTILES - 1) STAGE(buf ^ 1, nt + 1);

        // ---- QK (16x16, swapped: mfma(K, Q)) ----
        const short* kbase = Kp + buf * 16384 + g * 256 + li * 8;
        f32x4 s0[2], s1[2];
        s0[0] = zero4(); s0[1] = zero4(); s1[0] = zero4(); s1[1] = zero4();
        #pragma unroll
        for (int kc = 0; kc < 16; kc += 2) {
            #pragma unroll
            for (int fn = 0; fn < 2; ++fn) {
                bf16x8 ka  = *(const bf16x8*)&kbase[kc * 1024 + fn * 128];
                bf16x8 ka2 = *(const bf16x8*)&kbase[(kc + 1) * 1024 + fn * 128];
                s0[fn] = __builtin_amdgcn_mfma_f32_16x16x32_bf16(ka,  qf[kc],     s0[fn], 0, 0, 0);
                s1[fn] = __builtin_amdgcn_mfma_f32_16x16x32_bf16(ka2, qf[kc + 1], s1[fn], 0, 0, 0);
            }
        }
        // softmax (no-max) + P write: P[q = w*16+li][key = fn*16+g*4+i]
        #pragma unroll
        for (int fn = 0; fn < 2; ++fn) {
            float e0 = exp2f((s0[fn][0] + s1[fn][0]) * SC);
            float e1 = exp2f((s0[fn][1] + s1[fn][1]) * SC);
            float e2 = exp2f((s0[fn][2] + s1[fn][2]) * SC);
            float e3 = exp2f((s0[fn][3] + s1[fn][3]) * SC);
            lsum += (e0 + e1) + (e2 + e3);
            union { __hip_bfloat162 h; unsigned u; } p01, p23;
            p01.h = __float22bfloat162_rn(make_float2(e0, e1));
            p23.h = __float22bfloat162_rn(make_float2(e2, e3));
            *(uint2*)&Pp[(w * 16 + li) * 40 + fn * 16 + g * 4] = make_uint2(p01.u, p23.u);
        }
        __syncthreads();   // P visible; K(buf) consumed

        // ---- PV (32x32x16): C[ch][q] += V[ch][k] * P[q][k] ----
        const short* vbase = Vp + buf * 20480 + (size_t)w * 64 * 40;
        bf16x8 vf[2][2];
        #pragma unroll
        for (int cht = 0; cht < 2; ++cht)
            #pragma unroll
            for (int kx = 0; kx < 2; ++kx)
                vf[cht][kx] = *(const bf16x8*)&vbase[(cht * 32 + l31) * 40 + kx * 16 + l5 * 8];
        #pragma unroll
        for (int q2 = 0; q2 < 4; ++q2) {
            #pragma unroll
            for (int kx = 0; kx < 2; ++kx) {
                bf16x8 pf = *(const bf16x8*)&Pp[(q2 * 32 + l31) * 40 + kx * 16 + l5 * 8];
                oacc[q2 * 2 + 0] = __builtin_amdgcn_mfma_f32_32x32x16_bf16(vf[0][kx], pf, oacc[q2 * 2 + 0], 0, 0, 0);
                oacc[q2 * 2 + 1] = __builtin_amdgcn_mfma_f32_32x32x16_bf16(vf[1][kx], pf, oacc[q2 * 2 + 1], 0, 0, 0);
            }
        }
        __syncthreads();   // staged loads drained; P free for next tile
        buf ^= 1;
    }

    // row-sum partials (wave w owns queries w*16..w*16+15; query = li)
    lsum += __shfl_xor(lsum, 16);
    lsum += __shfl_xor(lsum, 32);
    float* Lb = (ks ? L1 : L0) + (size_t)b * HW + m0 + w * 16;
    if (lane < 16) Lb[lane] = lsum;

    // O epilogue: per-wave LDS transpose (144B rows) -> coalesced [b][m][c]
    short* tp = pool + w * 9216;
    #pragma unroll
    for (int a = 0; a < 8; ++a) {
        int q2 = a >> 1, cht = a & 1;
        int q_l = q2 * 32 + l31;
        #pragma unroll
        for (int rq = 0; rq < 4; ++rq) {
            int chb = cht * 32 + rq * 8 + l5 * 4;
            union { __hip_bfloat162 h; unsigned u; } x01, x23;
            x01.h = __float22bfloat162_rn(make_float2(oacc[a][rq * 4 + 0], oacc[a][rq * 4 + 1]));
            x23.h = __float22bfloat162_rn(make_float2(oacc[a][rq * 4 + 2], oacc[a][rq * 4 + 3]));
            *(uint2*)&tp[q_l * 72 + chb] = make_uint2(x01.u, x23.u);
        }
    }
    asm volatile("s_waitcnt lgkmcnt(0)" ::: "memory");
    __builtin_amdgcn_sched_barrier(0);
    short* Ob = (ks ? O1 : O0) + ((size_t)b * HW + m0) * C_DIM + w * 64;
    #pragma unroll
    for (int qg = 0; qg < 16; ++qg) {
        int qr = qg * 8 + (lane >> 3);
        bf16x8 v = *(const bf16x8*)&tp[qr * 72 + (lane & 7) * 8];
        *(bf16x8*)&Ob[(size_t)qr * C_DIM + (lane & 7) * 8] = v;
    }
}

__global__ void k_att_comb(const short* __restrict__ O0, const short* __restrict__ O1,
                           const float* __restrict__ L0, const float* __restrict__ L1,
                           short* __restrict__ oatt) {
    int i = blockIdx.x * 256 + threadIdx.x;
    int row = i >> 6;
    int c0 = (i & 63) * 8;
    float r = 1.0f / (L0[row] + L1[row]);
    size_t base = (size_t)row * C_DIM + c0;
    bf16x8 a = *(const bf16x8*)&O0[base];
    bf16x8 c = *(const bf16x8*)&O1[base];
    bf16x8 o;
    #pragma unroll
    for (int j = 0; j < 8; ++j)
        o[j] = f2b((b2f(a[j]) + b2f(c[j])) * r);
    *(bf16x8*)&oatt[base] = o;
}

// ---------------- launch ----------------
extern "C" void kernel_launch(void* const* d_in, const int* in_sizes, int n_in,
                              void* d_out, int out_size, void* d_ws, size_t ws_size,
                              hipStream_t stream) {
    const float* x    = (const float*)d_in[0];
    const float* ln_w = (const float*)d_in[1];
    const float* ln_b = (const float*)d_in[2];
    const float* wq   = (const float*)d_in[3];
    const float* wk   = (const float*)d_in[4];
    const float* wv   = (const float*)d_in[5];
    const float* wp   = (const float*)d_in[6];
    const float* bp   = (const float*)d_in[7];
    float* out = (float*)d_out;

    char* ws = (char*)d_ws;
    size_t off = 0;
    auto alloc = [&](size_t bytes) {
        char* p = ws + off;
        off += (bytes + 255) & ~(size_t)255;
        return p;
    };
    short* hp   = (short*)alloc((size_t)BATCH * PPIX * C_DIM * 2);   // also O-partial 0
    short* wqb  = (short*)alloc((size_t)512 * 512 * 2);
    short* wkr  = (short*)alloc((size_t)512 * 4608 * 2);
    short* wvr  = (short*)alloc((size_t)512 * 4608 * 2);
    short* wpb  = (short*)alloc((size_t)512 * 512 * 2);
    short* qT   = (short*)alloc((size_t)BATCH * HW * C_DIM * 2);
    short* kT   = (short*)alloc((size_t)BATCH * HW * C_DIM * 2);
    short* vg   = (short*)alloc((size_t)BATCH * HW * C_DIM * 2);
    short* oatt = (short*)alloc((size_t)BATCH * HW * C_DIM * 2);     // also O-partial 1
    float* mean = (float*)alloc((size_t)BATCH * HW * 4);             // also Lsum 0
    float* rstd = (float*)alloc((size_t)BATCH * HW * 4);             // also Lsum 1

    hipMemsetAsync(hp, 0, (size_t)BATCH * PPIX * C_DIM * 2, stream);
    k_cvt_bf16<<<1024, 256, 0, stream>>>(wq, wqb, 512 * 512);
    k_cvt_bf16<<<1024, 256, 0, stream>>>(wp, wpb, 512 * 512);
    k_reorder_w3<<<9216, 256, 0, stream>>>(wk, wkr);
    k_reorder_w3<<<9216, 256, 0, stream>>>(wv, wvr);
    k_ln_stats<<<512, 256, 0, stream>>>(x, mean, rstd);
    k_ln_apply<<<2048, 256, 0, stream>>>(x, mean, rstd, ln_w, ln_b, hp);

    k_gemm<1, 0, 0><<<512, 256, 0, stream>>>(hp, wqb, qT, nullptr, nullptr);
    k_gemm_kv<<<512, 256, 0, stream>>>(hp, wkr, wvr, kT, vg);

    short* Op0 = hp;
    short* Op1 = oatt;
    float* Ls0 = mean;
    float* Ls1 = rstd;
    k_attn<<<256, 512, 0, stream>>>(qT, kT, vg, Op0, Op1, Ls0, Ls1);
    k_att_comb<<<4096, 256, 0, stream>>>(Op0, Op1, Ls0, Ls1, oatt);

    k_gemm<1, 1, 2><<<512, 256, 0, stream>>>(oatt, wpb, out, bp, x);
}